// Round 8
// baseline (16764.360 us; speedup 1.0000x reference)
//
#include <hip/hip_runtime.h>

// ---------------------------------------------------------------------------
// Encoder: B=64, T=2048, D=256, U=256, UEP=64
//  Phase 1a: s1  = ln(x @ W + b)    -> f16   [131072][768]
//  Phase 1b: s1e = ln(x @ W_EP + b) -> f64   [131072][192]  (exact fp64)
//  Phase 2 : 64 WGs x 512 thr, 2048 steps, 4 RAW barriers/step.
//    KEY CHANGE (R8): eliminate LDS broadcast-read waste.
//      - h / rh GEMV operands distributed 1 word/lane (unique ds_read) and
//        broadcast via v_readlane (VALU) -> ~400KB/step less LDS traffic.
//      - Uzr streamed from L2 per step (two 16-chunk halves, latency hidden
//        under EP fp64 half-dots / is_end / prefetch issue).
//    Uh stays in LDS (unique-addr reads). EP GRU + is_end: unchanged fp64.
// ---------------------------------------------------------------------------

typedef _Float16 h2  __attribute__((ext_vector_type(2)));
typedef _Float16 v8h __attribute__((ext_vector_type(8)));

__device__ __forceinline__ float fdot2_(h2 a, h2 b, float c) {
#if __has_builtin(__builtin_amdgcn_fdot2)
  return __builtin_amdgcn_fdot2(a, b, c, false);
#else
  return c + (float)a[0] * (float)b[0] + (float)a[1] * (float)b[1];
#endif
}

template <int I>
__device__ __forceinline__ h2 pr(v8h v) {
  h2 r; r[0] = v[2 * I]; r[1] = v[2 * I + 1]; return r;
}

// broadcast word k of a distributed register across the wave (VALU, no LDS)
__device__ __forceinline__ h2 rl2(int wreg, int k) {
  return __builtin_bit_cast(h2, __builtin_amdgcn_readlane(wreg, k));
}

// Raw barrier: order LDS (lgkmcnt) but leave global loads/stores in flight.
__device__ __forceinline__ void wg_barrier() {
  __builtin_amdgcn_sched_barrier(0);
  asm volatile("s_waitcnt lgkmcnt(0)" ::: "memory");
  __builtin_amdgcn_sched_barrier(0);
  __builtin_amdgcn_s_barrier();
  __builtin_amdgcn_sched_barrier(0);
}

// ---------------------------------------------------------------------------
// prep: weight transposes / conversions.
// blocks: [0,768) wt | [768,1280) uzr | [1280,1536) uh chunk-major | [1536,1728) wept
// ---------------------------------------------------------------------------
__global__ __launch_bounds__(256) void prep_kernel(
    const float* __restrict__ W, const float* __restrict__ U,
    const float* __restrict__ W_EP,
    _Float16* __restrict__ wt, _Float16* __restrict__ uzr,
    _Float16* __restrict__ uh, float* __restrict__ wept)
{
  const int blk = blockIdx.x;
  const int k = threadIdx.x;
  if (blk < 768) {                       // wt[j][k] = W[k][j]  (f16)
    const int j = blk;
    wt[(size_t)j * 256 + k] = (_Float16)W[(size_t)k * 768 + j];
  } else if (blk < 1280) {               // uzr[j][k] = U[k][j], j<512 (f16)
    const int j = blk - 768;
    uzr[(size_t)j * 256 + k] = (_Float16)U[(size_t)k * 768 + j];
  } else if (blk < 1536) {               // uh chunk-major: page p=k>>3, elem k&7
    const int j = blk - 1280;            // col 0..255
    const int p = k >> 3, e = k & 7;
    uh[((size_t)p * 256 + j) * 8 + e] = (_Float16)U[(size_t)k * 768 + 512 + j];
  } else {                               // wept[j][k] = W_EP[k][j] (f32)
    const int j = blk - 1536;
    wept[(size_t)j * 256 + k] = W_EP[(size_t)k * 192 + j];
  }
}

// ---------------------------------------------------------------------------
// Phase 1a: main s1 = ln(x@W + b, gammas[0], betas[0]) stored f16.
// ---------------------------------------------------------------------------
__global__ __launch_bounds__(256) void ph1_main_kernel(
    const float* __restrict__ x, const _Float16* __restrict__ wt,
    const float* __restrict__ bvec, const float* __restrict__ gam,
    const float* __restrict__ bet, _Float16* __restrict__ s1out)
{
  __shared__ __align__(16) _Float16 xs[16][256];   // 8 KB
  __shared__ float sp[16][768];                    // 48 KB
  const int tid = threadIdx.x;
  const size_t row0 = (size_t)blockIdx.x * 16;

  #pragma unroll
  for (int i = 0; i < 16; ++i)
    xs[i][tid] = (_Float16)x[(row0 + i) * 256 + tid];
  __syncthreads();

  #pragma unroll 1
  for (int cc = 0; cc < 3; ++cc) {
    const int col = cc * 256 + tid;
    const v8h* wp = (const v8h*)(wt + (size_t)col * 256);
    float acc[16];
    #pragma unroll
    for (int r = 0; r < 16; ++r) acc[r] = 0.f;
    #pragma unroll 4
    for (int c = 0; c < 32; ++c) {
      const v8h w8 = wp[c];
      #pragma unroll
      for (int r = 0; r < 16; ++r) {
        const v8h x8 = *(const v8h*)(&xs[r][c * 8]);
        acc[r] = fdot2_(pr<0>(x8), pr<0>(w8), acc[r]);
        acc[r] = fdot2_(pr<1>(x8), pr<1>(w8), acc[r]);
        acc[r] = fdot2_(pr<2>(x8), pr<2>(w8), acc[r]);
        acc[r] = fdot2_(pr<3>(x8), pr<3>(w8), acc[r]);
      }
    }
    const float bb = bvec[col];
    #pragma unroll
    for (int r = 0; r < 16; ++r) sp[r][col] = acc[r] + bb;
  }
  __syncthreads();

  const int w = tid >> 6, lane = tid & 63;
  for (int rr = 0; rr < 4; ++rr) {
    const int r = (w << 2) | rr;
    float vals[12], sum = 0.f, sq = 0.f;
    #pragma unroll
    for (int j = 0; j < 12; ++j) {
      const float v = sp[r][lane + (j << 6)];
      vals[j] = v; sum += v; sq += v * v;
    }
    #pragma unroll
    for (int m = 32; m >= 1; m >>= 1) {
      sum += __shfl_xor(sum, m); sq += __shfl_xor(sq, m);
    }
    const float mean = sum * (1.f / 768.f);
    const float var = sq * (1.f / 768.f) - mean * mean;
    const float inv = 1.f / (sqrtf(var + 1e-5f) + 1e-5f);
    #pragma unroll
    for (int j = 0; j < 12; ++j) {
      const int c = lane + (j << 6);
      s1out[(row0 + r) * 768 + c] =
          (_Float16)(gam[c] * ((vals[j] - mean) * inv) + bet[c]);
    }
  }
}

// ---------------------------------------------------------------------------
// Phase 1b: EP s1e = ln(x@W_EP + b_EP) in exact fp64, stored f64 (or f32).
// ---------------------------------------------------------------------------
__global__ __launch_bounds__(192) void ph1_ep_kernel(
    const float* __restrict__ x, const float* __restrict__ wept,
    const float* __restrict__ bvec, const float* __restrict__ gam,
    const float* __restrict__ bet, void* __restrict__ s1e, const int store64)
{
  __shared__ __align__(16) float xs[16][256];   // 16 KB
  __shared__ double sp[16][192];                // 24 KB
  const int tid = threadIdx.x;
  const size_t row0 = (size_t)blockIdx.x * 16;

  for (int idx = tid; idx < 4096; idx += 192)
    xs[idx >> 8][idx & 255] = x[row0 * 256 + idx];
  __syncthreads();

  {
    const float4* wp = (const float4*)(wept + (size_t)tid * 256);
    double acc[16];
    #pragma unroll
    for (int r = 0; r < 16; ++r) acc[r] = 0.0;
    #pragma unroll 2
    for (int c = 0; c < 64; ++c) {
      const float4 w4 = wp[c];
      #pragma unroll
      for (int r = 0; r < 16; ++r) {
        const float4 x4 = *(const float4*)(&xs[r][c * 4]);
        acc[r] += (double)x4.x * (double)w4.x;
        acc[r] += (double)x4.y * (double)w4.y;
        acc[r] += (double)x4.z * (double)w4.z;
        acc[r] += (double)x4.w * (double)w4.w;
      }
    }
    const double bb = (double)bvec[tid];
    #pragma unroll
    for (int r = 0; r < 16; ++r) sp[r][tid] = acc[r] + bb;
  }
  __syncthreads();

  const int w = tid >> 6, lane = tid & 63;
  for (int r = w; r < 16; r += 3) {
    double vals[3], sum = 0.0, sq = 0.0;
    #pragma unroll
    for (int j = 0; j < 3; ++j) {
      const double v = sp[r][lane + (j << 6)];
      vals[j] = v; sum += v; sq += v * v;
    }
    #pragma unroll
    for (int m = 32; m >= 1; m >>= 1) {
      sum += __shfl_xor(sum, m); sq += __shfl_xor(sq, m);
    }
    const double mean = sum * (1.0 / 192.0);
    const double var = sq * (1.0 / 192.0) - mean * mean;
    const double den = sqrt(var + 1e-5) + 1e-5;
    #pragma unroll
    for (int j = 0; j < 3; ++j) {
      const int c = lane + (j << 6);
      const double vv = (double)gam[c] * ((vals[j] - mean) / den) + (double)bet[c];
      if (store64) ((double*)s1e)[(row0 + r) * 192 + c] = vv;
      else         ((float*)s1e)[(row0 + r) * 192 + c] = (float)vv;
    }
  }
}

// ---------------------------------------------------------------------------
// Phase 2 LDS map (dynamic, 144192 B)
// ---------------------------------------------------------------------------
#define OFF_UH     0        /* 131072  f16 Uh chunk-major [32 pages][256 cols][8] */
#define OFF_MASK   131072   /* 8192    int mask row                               */
#define OFF_HEP    139264   /* 512     f64 hep[64]                                */
#define OFF_ZEE    139776   /* 512     f64 ze[64]                                 */
#define OFF_RHEP   140288   /* 512     f64 rhep[64]                               */
#define OFF_EPZRP  140800   /* 128     double2 epzrP[8]                           */
#define OFF_EPHHP  140928   /* 64      double2 ephhP[4]                           */
#define OFF_H2     140992   /* 512     f16 h packed h2[128]                       */
#define OFF_RH     141504   /* 512     f16 rh packed                              */
#define OFF_HF     142016   /* 1024    f32 h[256]                                 */
#define OFF_Z      143040   /* 1024    f32 z[256]                                 */
#define OFF_ZRP    144064   /* 64      float2 zrP[8]                              */
#define OFF_HHP    144128   /* 32      float2 hhP[4]                              */
#define OFF_FLAG   144160   /* 8       f32 flag[2]                                */
#define SCAN_LDS_BYTES 144192

__global__ __launch_bounds__(512, 2) void scan_kernel(
    const _Float16* __restrict__ uzr_g, const _Float16* __restrict__ uh_g,
    const float* __restrict__ U_EP, const _Float16* __restrict__ s1,
    const void* __restrict__ s1e_v, const int s1e64,
    const int* __restrict__ mask,
    const float* __restrict__ gam1, const float* __restrict__ bet1,
    const float* __restrict__ gamep1, const float* __restrict__ betep1,
    const float* __restrict__ W1, const float* __restrict__ b1,
    float* __restrict__ out)
{
  extern __shared__ char sm[];
  const int t = threadIdx.x;
  const int b = blockIdx.x;
  const int w = t >> 6;
  const int lane = t & 63;
  const int je  = t >> 2;            // EP-zr col 0..127
  const int qe  = t & 3;             // EP K-slice
  const int jeh = (t & 255) >> 2;    // EP-hh col 0..63

  float*  hf    = (float*)(sm + OFF_HF);
  float*  flagp = (float*)(sm + OFF_FLAG);
  double* hepd  = (double*)(sm + OFF_HEP);
  int*    maskl = (int*)(sm + OFF_MASK);

  // ---- stage Uh (linear copy; layout already chunk-major) ----
  {
    const v8h* src = (const v8h*)uh_g;
    v8h* dst = (v8h*)(sm + OFF_UH);
    #pragma unroll
    for (int i = 0; i < 16; ++i) dst[i * 512 + t] = src[i * 512 + t];
  }
  // ---- stage mask row ----
  #pragma unroll
  for (int i = 0; i < 4; ++i) maskl[i * 512 + t] = mask[((size_t)b << 11) + i * 512 + t];

  // ---- EP weights (f32 regs) ----
  float uez[16], ueh[16];
  #pragma unroll
  for (int i = 0; i < 16; ++i) uez[i] = U_EP[(size_t)(16 * qe + i) * 192 + je];
  #pragma unroll
  for (int i = 0; i < 16; ++i) ueh[i] = U_EP[(size_t)(16 * qe + i) * 192 + 128 + jeh];

  // ---- constants ----
  const float gz = gam1[t],                bz = bet1[t];
  const float gh = gam1[512 + (t & 255)],  bh = bet1[512 + (t & 255)];
  const float gse = gamep1[je],            bse = betep1[je];
  const float ghe = gamep1[128 + jeh],     bhe = betep1[128 + jeh];
  const double w1d = (double)W1[lane];
  const double b1d = (double)b1[0];
  const double* dptr = (const double*)s1e_v;
  const float*  fptr = (const float*)s1e_v;
  const v8h* up = (const v8h*)uzr_g + (size_t)t * 32;   // column t, 32 chunks

  // ---- init state ----
  if (t < 128) { h2 z2; z2[0] = (_Float16)0.f; z2[1] = (_Float16)0.f;
                 ((h2*)(sm + OFF_H2))[t] = z2; }
  if (t < 256) hf[t] = 0.f;
  if (t < 64)  hepd[t] = 0.0;
  if (t < 2)   flagp[t] = 0.f;

  // ---- prefetch step 0 ----
  const size_t n0 = (size_t)b << 11;
  float  s1zr_c = (float)s1[n0 * 768 + t];
  float  s1h_c  = (float)s1[n0 * 768 + 512 + (t & 255)];
  double s1ezr_c = s1e64 ? dptr[n0 * 192 + je]
                         : (double)fptr[n0 * 192 + je];
  double s1ehh_c = s1e64 ? dptr[n0 * 192 + 128 + jeh]
                         : (double)fptr[n0 * 192 + 128 + jeh];
  __syncthreads();

  for (int tt = 0; tt < 2048; ++tt) {
    const size_t n = ((size_t)b << 11) | (size_t)tt;
    const float fz = (flagp[tt & 1] > 0.5f) ? 0.f : 1.f;

    // ---- Seg1 ----
    if (tt > 0 && t < 256) out[(n - 1) * 256 + t] = hf[t];

    // stream first half of Uzr column (chunks 0..15)
    v8h wz[16];
    #pragma unroll
    for (int c = 0; c < 16; ++c) wz[c] = up[c];

    // prefetch t+1 streaming data (issue only)
    const int ttn = (tt < 2047) ? tt + 1 : 2047;
    const size_t np1 = ((size_t)b << 11) | (size_t)ttn;
    const float  s1zr_n = (float)s1[np1 * 768 + t];
    const float  s1h_n  = (float)s1[np1 * 768 + 512 + (t & 255)];
    const double s1ezr_n = s1e64 ? dptr[np1 * 192 + je]
                                 : (double)fptr[np1 * 192 + je];
    const double s1ehh_n = s1e64 ? dptr[np1 * 192 + 128 + jeh]
                                 : (double)fptr[np1 * 192 + 128 + jeh];

    // distribute h: one h2-word per lane (unique LDS reads, 512B/wave)
    const int* h2i = (const int*)(sm + OFF_H2);
    const int hw0 = h2i[lane];
    const int hw1 = h2i[64 + lane];

    // EP-zr dot, first half (i = 0..3)  [unchanged math/order]
    double de;
    {
      const double2* hp = (const double2*)(hepd + 16 * qe);
      double acc = 0.0;
      #pragma unroll
      for (int i = 0; i < 4; ++i) {
        const double2 hv2 = hp[i];
        acc += hv2.x * (double)uez[2 * i] + hv2.y * (double)uez[2 * i + 1];
      }

      // zr dot, first half: chunks 0..15 (words 0..63 via hw0)
      float a0 = 0.f, a1 = 0.f, a2 = 0.f, a3 = 0.f;
      #pragma unroll
      for (int c = 0; c < 16; ++c) {
        const v8h wv = wz[c];
        a0 = fdot2_(rl2(hw0, 4 * c + 0), pr<0>(wv), a0);
        a1 = fdot2_(rl2(hw0, 4 * c + 1), pr<1>(wv), a1);
        a2 = fdot2_(rl2(hw0, 4 * c + 2), pr<2>(wv), a2);
        a3 = fdot2_(rl2(hw0, 4 * c + 3), pr<3>(wv), a3);
      }

      // stream second half of Uzr column (chunks 16..31)
      #pragma unroll
      for (int c = 0; c < 16; ++c) wz[c] = up[16 + c];

      // EP-zr dot, second half (i = 4..7)
      #pragma unroll
      for (int i = 4; i < 8; ++i) {
        const double2 hv2 = hp[i];
        acc += hv2.x * (double)uez[2 * i] + hv2.y * (double)uez[2 * i + 1];
      }
      acc += __shfl_xor(acc, 1); acc += __shfl_xor(acc, 2);
      de = acc;
      double es = de, eq = de * de;
      #pragma unroll
      for (int m = 4; m <= 32; m <<= 1) { es += __shfl_xor(es, m); eq += __shfl_xor(eq, m); }
      if (lane == 0) ((double2*)(sm + OFF_EPZRP))[w] = make_double2(es, eq);

      // is_end from hep (pre-update), wave 7
      if (w == 7) {
        double p = hepd[lane] * w1d;
        #pragma unroll
        for (int m = 1; m <= 32; m <<= 1) p += __shfl_xor(p, m);
        if (t == 448) {
          const float e = ((p + b1d) > 0.0) ? 1.f : 0.f;
          flagp[(tt + 1) & 1] = e;
          out[(size_t)33554432 + n] = e;
        }
      }

      // zr dot, second half: chunks 16..31 (words 64..127 via hw1)
      #pragma unroll
      for (int c = 0; c < 16; ++c) {
        const v8h wv = wz[c];
        a0 = fdot2_(rl2(hw1, 4 * c + 0), pr<0>(wv), a0);
        a1 = fdot2_(rl2(hw1, 4 * c + 1), pr<1>(wv), a1);
        a2 = fdot2_(rl2(hw1, 4 * c + 2), pr<2>(wv), a2);
        a3 = fdot2_(rl2(hw1, 4 * c + 3), pr<3>(wv), a3);
      }
      const float d_ = ((a0 + a1) + (a2 + a3)) * fz;
      float s_ = d_, q_ = d_ * d_;
      #pragma unroll
      for (int m = 1; m <= 32; m <<= 1) { s_ += __shfl_xor(s_, m); q_ += __shfl_xor(q_, m); }
      if (lane == 0) ((float2*)(sm + OFF_ZRP))[w] = make_float2(s_, q_);

      // stash d for Seg2 (register)
      s_ = d_;  // reuse
      // store d into a named variable below via the enclosing scope:
      // (handled by moving LN into this scope)
      // ---- Seg2 main LN happens after barrier; keep d_ alive:
      wg_barrier();  // B1

      // ---- Seg2: LN512 -> z / rh | EP LN128 -> ze / rhep ----
      {
        float S = 0.f, Q = 0.f;
        const float4* zp = (const float4*)(sm + OFF_ZRP);
        #pragma unroll
        for (int i = 0; i < 4; ++i) { const float4 v = zp[i]; S += v.x + v.z; Q += v.y + v.w; }
        const float mean = S * (1.f / 512.f);
        const float var = Q * (1.f / 512.f) - mean * mean;
        const float inv = 1.f / (sqrtf(var + 1e-5f) + 1e-5f);
        const float s2v = gz * ((d_ - mean) * inv) + bz;
        float sv = 0.2f * (s1zr_c + s2v) + 0.5f;
        sv = fminf(fmaxf(sv, 0.f), 1.f);
        if (t < 256) ((float*)(sm + OFF_Z))[t] = sv;
        else {
          const float rhv = sv * (fz * hf[t - 256]);
          ((_Float16*)(sm + OFF_RH))[t - 256] = (_Float16)rhv;
        }
      }
      if ((t & 3) == 0) {               // EP-zr finish (128 threads)
        double S = 0.0, Q = 0.0;
        const double2* ep = (const double2*)(sm + OFF_EPZRP);
        #pragma unroll
        for (int i = 0; i < 8; ++i) { S += ep[i].x; Q += ep[i].y; }
        const double mean = S * (1.0 / 128.0);
        const double var = Q * (1.0 / 128.0) - mean * mean;
        const double den = sqrt(var + 1e-5) + 1e-5;
        const double s2e = (double)gse * ((de - mean) / den) + (double)bse;
        double se = 0.2 * (s1ezr_c + s2e) + 0.5;
        se = fmin(fmax(se, 0.0), 1.0);
        if (je < 64) ((double*)(sm + OFF_ZEE))[je] = se;
        else         ((double*)(sm + OFF_RHEP))[je - 64] = se * hepd[je - 64];
      }
    }
    wg_barrier();  // B2

    // ---- Seg3: hh dot (t<256; uh unique-addr LDS, rh via readlane) | EP-hh
    float dh = 0.f;
    double deh = 0.0;
    if (t < 256) {
      const int* rhi = (const int*)(sm + OFF_RH);
      const int rr0 = rhi[lane];
      const int rr1 = rhi[64 + lane];
      const v8h* uhv = (const v8h*)(sm + OFF_UH);
      float c0 = 0.f, c1 = 0.f, c2 = 0.f, c3 = 0.f;
      #pragma unroll
      for (int p = 0; p < 16; ++p) {
        const v8h uc = uhv[p * 256 + t];
        c0 = fdot2_(rl2(rr0, 4 * p + 0), pr<0>(uc), c0);
        c1 = fdot2_(rl2(rr0, 4 * p + 1), pr<1>(uc), c1);
        c2 = fdot2_(rl2(rr0, 4 * p + 2), pr<2>(uc), c2);
        c3 = fdot2_(rl2(rr0, 4 * p + 3), pr<3>(uc), c3);
      }
      #pragma unroll
      for (int p = 16; p < 32; ++p) {
        const v8h uc = uhv[p * 256 + t];
        c0 = fdot2_(rl2(rr1, 4 * (p - 16) + 0), pr<0>(uc), c0);
        c1 = fdot2_(rl2(rr1, 4 * (p - 16) + 1), pr<1>(uc), c1);
        c2 = fdot2_(rl2(rr1, 4 * (p - 16) + 2), pr<2>(uc), c2);
        c3 = fdot2_(rl2(rr1, 4 * (p - 16) + 3), pr<3>(uc), c3);
      }
      dh = (c0 + c1) + (c2 + c3);
      float s_ = dh, q_ = dh * dh;
      #pragma unroll
      for (int m = 1; m <= 32; m <<= 1) { s_ += __shfl_xor(s_, m); q_ += __shfl_xor(q_, m); }
      if (lane == 0) ((float2*)(sm + OFF_HHP))[w] = make_float2(s_, q_);
    } else {
      const double2* rp = (const double2*)((double*)(sm + OFF_RHEP) + 16 * qe);
      double acc = 0.0;
      #pragma unroll
      for (int i = 0; i < 8; ++i) {
        const double2 rv = rp[i];
        acc += rv.x * (double)ueh[2 * i] + rv.y * (double)ueh[2 * i + 1];
      }
      acc += __shfl_xor(acc, 1); acc += __shfl_xor(acc, 2);
      deh = acc;
      double es = deh, eq = deh * deh;
      #pragma unroll
      for (int m = 4; m <= 32; m <<= 1) { es += __shfl_xor(es, m); eq += __shfl_xor(eq, m); }
      if (lane == 0) ((double2*)(sm + OFF_EPHHP))[w - 4] = make_double2(es, eq);
    }
    wg_barrier();  // B3

    // ---- Seg4: main h update | EP hep update ----
    const int xm = maskl[tt];
    if (t < 256) {
      float S = 0.f, Q = 0.f;
      const float4* hp4 = (const float4*)(sm + OFF_HHP);
      #pragma unroll
      for (int i = 0; i < 2; ++i) { const float4 v = hp4[i]; S += v.x + v.z; Q += v.y + v.w; }
      const float mean = S * (1.f / 256.f);
      const float var = Q * (1.f / 256.f) - mean * mean;
      const float inv = 1.f / (sqrtf(var + 1e-5f) + 1e-5f);
      const float hhv = gh * ((dh - mean) * inv) + bh;
      const float z = ((float*)(sm + OFF_Z))[t];
      const float hzf = fz * hf[t];
      const float hn = z * hzf + (1.f - z) * tanhf(s1h_c + hhv);
      const float hc_ = (xm > 0) ? hn : hzf;
      hf[t] = hc_;
      const float ho = __shfl_xor(hc_, 1);
      if (!(t & 1)) {
        h2 p2; p2[0] = (_Float16)hc_; p2[1] = (_Float16)ho;
        ((h2*)(sm + OFF_H2))[t >> 1] = p2;
      }
    } else if ((t & 3) == 0) {          // EP finish (64 threads, col jeh)
      double S = 0.0, Q = 0.0;
      const double2* ep = (const double2*)(sm + OFF_EPHHP);
      #pragma unroll
      for (int i = 0; i < 4; ++i) { S += ep[i].x; Q += ep[i].y; }
      const double mean = S * (1.0 / 64.0);
      const double var = Q * (1.0 / 64.0) - mean * mean;
      const double den = sqrt(var + 1e-5) + 1e-5;
      const double hhe = (double)ghe * ((deh - mean) / den) + (double)bhe;
      const double ze = ((double*)(sm + OFF_ZEE))[jeh];
      const double hold = hepd[jeh];
      const double hepn = ze * hold + (1.0 - ze) * tanh(s1ehh_c + hhe);
      hepd[jeh] = (xm > 0) ? hepn : hold;
    }
    wg_barrier();  // B4

    s1zr_c = s1zr_n; s1h_c = s1h_n; s1ezr_c = s1ezr_n; s1ehh_c = s1ehh_n;
  }
  // final h write (step 2047)
  if (t < 256) out[((((size_t)b << 11) | 2047)) * 256 + t] = hf[t];
}

// ---------------------------------------------------------------------------
extern "C" void kernel_launch(void* const* d_in, const int* in_sizes, int n_in,
                              void* d_out, int out_size, void* d_ws, size_t ws_size,
                              hipStream_t stream)
{
  (void)in_sizes; (void)n_in; (void)out_size;
  const float* x       = (const float*)d_in[0];
  const int*   mask    = (const int*)d_in[1];
  const float* W       = (const float*)d_in[2];
  const float* U       = (const float*)d_in[3];
  const float* bvec    = (const float*)d_in[4];
  const float* gammas  = (const float*)d_in[5];
  const float* betas   = (const float*)d_in[6];
  const float* W_EP    = (const float*)d_in[7];
  const float* U_EP    = (const float*)d_in[8];
  const float* b_EP    = (const float*)d_in[9];
  const float* gammasE = (const float*)d_in[10];
  const float* betasE  = (const float*)d_in[11];
  const float* W1_EP   = (const float*)d_in[12];
  const float* b1_EP   = (const float*)d_in[13];
  float* out = (float*)d_out;

  const size_t NR = 131072;                 // B*T
  const size_t S1_SZ    = NR * 768 * 2;     // f16
  const size_t S1E64_SZ = NR * 192 * 8;     // f64
  const size_t S1E32_SZ = NR * 192 * 4;     // f32 fallback
  const size_t WSMALL = 262144 + 131072 + 393216 + 196608;
  const int s1e64 = (ws_size >= S1_SZ + S1E64_SZ + WSMALL) ? 1 : 0;
  const size_t S1E_SZ = s1e64 ? S1E64_SZ : S1E32_SZ;
  if (ws_size < S1_SZ + S1E32_SZ + WSMALL) return;  // cannot run

  char* ws = (char*)d_ws;
  size_t off = 0;
  void* s1e      = (void*)(ws + off);      off += S1E_SZ;
  _Float16* s1   = (_Float16*)(ws + off);  off += S1_SZ;
  _Float16* uzr  = (_Float16*)(ws + off);  off += 262144;
  _Float16* uh   = (_Float16*)(ws + off);  off += 131072;
  _Float16* wt   = (_Float16*)(ws + off);  off += 393216;
  float* wept    = (float*)(ws + off);     off += 196608;

  prep_kernel<<<dim3(1728), dim3(256), 0, stream>>>(
      W, U, W_EP, wt, uzr, uh, wept);
  ph1_main_kernel<<<dim3(8192), dim3(256), 0, stream>>>(
      x, wt, bvec, gammas, betas, s1);
  ph1_ep_kernel<<<dim3(8192), dim3(192), 0, stream>>>(
      x, wept, b_EP, gammasE, betasE, s1e, s1e64);

  hipFuncSetAttribute(reinterpret_cast<const void*>(scan_kernel),
                      hipFuncAttributeMaxDynamicSharedMemorySize, SCAN_LDS_BYTES);
  scan_kernel<<<dim3(64), dim3(512), SCAN_LDS_BYTES, stream>>>(
      uzr, uh, U_EP, s1, (const void*)s1e, s1e64, mask,
      gammas + 768, betas + 768, gammasE + 192, betasE + 192,
      W1_EP, b1_EP, out);
}